// Round 2
// baseline (502.288 us; speedup 1.0000x reference)
//
#include <hip/hip_runtime.h>
#include <hip/hip_bf16.h>

#define N_NODES  50000
#define N_EDGES  800000
#define N_GRAPHS 64

typedef __bf16 bf16;
typedef __attribute__((ext_vector_type(8))) __bf16 bf16x8;
typedef __attribute__((ext_vector_type(4))) float f32x4;

#define MT 64          // rows (nodes) per block in the MLP kernel
#define HP 264         // padded LDS row length in bf16 (256 + 8 pad)

// ---------------------------------------------------------------------------
// Weight transpose + downconvert: w[k][n] fp32 (k-major) -> wT[n][k] bf16
// (n-major, k contiguous) so MFMA B-fragment loads are single 16B loads.
// ---------------------------------------------------------------------------
__global__ void transpose_w(const float* __restrict__ w1, const float* __restrict__ w2,
                            const float* __restrict__ w3,
                            bf16* __restrict__ wT1, bf16* __restrict__ wT2,
                            bf16* __restrict__ wT3) {
    int i = blockIdx.x * 256 + threadIdx.x;
    if (i < 65536) {                       // w1: 256x256
        int n = i >> 8, k = i & 255;
        wT1[n * 256 + k] = (bf16)w1[k * 256 + n];
    } else if (i < 131072) {               // w2: 256x256
        int j = i - 65536;
        int n = j >> 8, k = j & 255;
        wT2[n * 256 + k] = (bf16)w2[k * 256 + n];
    } else if (i < 163840) {               // w3: 256x128
        int j = i - 131072;
        int n = j >> 8, k = j & 255;       // n in [0,128)
        wT3[n * 256 + k] = (bf16)w3[k * 128 + n];
    }
}

// ---------------------------------------------------------------------------
// Edge scatter-add: agg[col[e]][f] += edge_attr[e][f]  (fp32 accumulation)
// ---------------------------------------------------------------------------
__global__ __launch_bounds__(256) void scatter_kernel(const float* __restrict__ ea,
                                                      const int* __restrict__ col,
                                                      float* __restrict__ agg) {
    int i = blockIdx.x * 256 + threadIdx.x;   // 51.2M total, fits int
    int e = i >> 6, f = i & 63;
    int c = col[e];
    atomicAdd(agg + (size_t)c * 64 + f, ea[i]);
}

// ---------------------------------------------------------------------------
// GEMM layer for N=256 (layers 1 & 2): h_in(64x256) @ wT(256x256) -> h_out
// 4 waves, each owns 64 columns: 4 m-tiles x 4 n-tiles of 16x16, K=256.
// ---------------------------------------------------------------------------
template <bool LEAKY>
__device__ __forceinline__ void gemm256(const bf16 (*hin)[HP],
                                        const bf16* __restrict__ wT,
                                        const float* __restrict__ bias,
                                        bf16 (*hout)[HP]) {
    const int lane = threadIdx.x & 63;
    const int wave = threadIdx.x >> 6;
    const int lr = lane & 15;   // A: m, B: n, C/D: col
    const int lq = lane >> 4;   // quad
    const int n0 = wave * 64;

    f32x4 acc[4][4];
#pragma unroll
    for (int a = 0; a < 4; a++)
#pragma unroll
        for (int b = 0; b < 4; b++) acc[a][b] = (f32x4)(0.f);

#pragma unroll
    for (int k0 = 0; k0 < 256; k0 += 32) {
        bf16x8 afrag[4], bfrag[4];
#pragma unroll
        for (int mt = 0; mt < 4; mt++)
            afrag[mt] = __builtin_bit_cast(bf16x8,
                *(const uint4*)&hin[mt * 16 + lr][k0 + lq * 8]);
#pragma unroll
        for (int nt = 0; nt < 4; nt++)
            bfrag[nt] = __builtin_bit_cast(bf16x8,
                *(const uint4*)(wT + (size_t)(n0 + nt * 16 + lr) * 256 + k0 + lq * 8));
#pragma unroll
        for (int mt = 0; mt < 4; mt++)
#pragma unroll
            for (int nt = 0; nt < 4; nt++)
                acc[mt][nt] = __builtin_amdgcn_mfma_f32_16x16x32_bf16(
                    afrag[mt], bfrag[nt], acc[mt][nt], 0, 0, 0);
    }

    // Epilogue: bias (+ leaky relu), bf16, into LDS.
    // C/D layout: col = lane&15, row = (lane>>4)*4 + i   [m89/m91 verified]
#pragma unroll
    for (int nt = 0; nt < 4; nt++) {
        int n = n0 + nt * 16 + lr;
        float bv = bias[n];
#pragma unroll
        for (int mt = 0; mt < 4; mt++) {
#pragma unroll
            for (int i = 0; i < 4; i++) {
                int row = mt * 16 + lq * 4 + i;
                float v = acc[mt][nt][i] + bv;
                if (LEAKY) v = (v >= 0.f) ? v : 0.01f * v;
                hout[row][n] = (bf16)v;
            }
        }
    }
}

// ---------------------------------------------------------------------------
// Final layer: h(64x256) @ wT3(128x256 n-major) + b3 -> out (global, fp32)
// ---------------------------------------------------------------------------
__device__ __forceinline__ void gemm_out(const bf16 (*hin)[HP],
                                         const bf16* __restrict__ wT3,
                                         const float* __restrict__ b3,
                                         float* __restrict__ out, int r0) {
    const int lane = threadIdx.x & 63;
    const int wave = threadIdx.x >> 6;
    const int lr = lane & 15;
    const int lq = lane >> 4;
    const int n0 = wave * 32;   // each wave owns 32 of the 128 output cols

    f32x4 acc[4][2];
#pragma unroll
    for (int a = 0; a < 4; a++)
#pragma unroll
        for (int b = 0; b < 2; b++) acc[a][b] = (f32x4)(0.f);

#pragma unroll
    for (int k0 = 0; k0 < 256; k0 += 32) {
        bf16x8 afrag[4], bfrag[2];
#pragma unroll
        for (int mt = 0; mt < 4; mt++)
            afrag[mt] = __builtin_bit_cast(bf16x8,
                *(const uint4*)&hin[mt * 16 + lr][k0 + lq * 8]);
#pragma unroll
        for (int nt = 0; nt < 2; nt++)
            bfrag[nt] = __builtin_bit_cast(bf16x8,
                *(const uint4*)(wT3 + (size_t)(n0 + nt * 16 + lr) * 256 + k0 + lq * 8));
#pragma unroll
        for (int mt = 0; mt < 4; mt++)
#pragma unroll
            for (int nt = 0; nt < 2; nt++)
                acc[mt][nt] = __builtin_amdgcn_mfma_f32_16x16x32_bf16(
                    afrag[mt], bfrag[nt], acc[mt][nt], 0, 0, 0);
    }

#pragma unroll
    for (int nt = 0; nt < 2; nt++) {
        int n = n0 + nt * 16 + lr;
        float bv = b3[n];
#pragma unroll
        for (int mt = 0; mt < 4; mt++) {
#pragma unroll
            for (int i = 0; i < 4; i++) {
                int row = mt * 16 + lq * 4 + i;
                int r = r0 + row;
                if (r < N_NODES) {
                    out[(size_t)r * 128 + n] = acc[mt][nt][i] + bv;
                }
            }
        }
    }
}

// ---------------------------------------------------------------------------
// Fused MLP: build h = [x | agg | u[batch]] (bf16) in LDS, then 3 GEMMs.
// ---------------------------------------------------------------------------
__global__ __launch_bounds__(256) void mlp_kernel(
    const float* __restrict__ x, const float* __restrict__ agg,
    const float* __restrict__ u, const int* __restrict__ batch,
    const bf16* __restrict__ wT1, const float* __restrict__ b1,
    const bf16* __restrict__ wT2, const float* __restrict__ b2,
    const bf16* __restrict__ wT3, const float* __restrict__ b3,
    float* __restrict__ out) {
    __shared__ bf16 hA[MT][HP];
    __shared__ bf16 hB[MT][HP];

    const int tid = threadIdx.x;
    const int r0 = blockIdx.x * MT;

    // --- Stage h = [x(128) | agg(64) | u[batch](64)] fp32 -> bf16 into hA ---
    // x part: 64 rows x 32 chunks of 4 floats
    for (int i = tid; i < MT * 32; i += 256) {
        int row = i >> 5, c4 = (i & 31) * 4;
        int r = r0 + row;
        float4 v = make_float4(0.f, 0.f, 0.f, 0.f);
        if (r < N_NODES) v = *(const float4*)(x + (size_t)r * 128 + c4);
        bf16* dst = &hA[row][c4];
        dst[0] = (bf16)v.x; dst[1] = (bf16)v.y; dst[2] = (bf16)v.z; dst[3] = (bf16)v.w;
    }
    // agg part: 64 rows x 16 chunks of 4 floats
    for (int i = tid; i < MT * 16; i += 256) {
        int row = i >> 4, c4 = (i & 15) * 4;
        int r = r0 + row;
        float4 v = make_float4(0.f, 0.f, 0.f, 0.f);
        if (r < N_NODES) v = *(const float4*)(agg + (size_t)r * 64 + c4);
        bf16* dst = &hA[row][128 + c4];
        dst[0] = (bf16)v.x; dst[1] = (bf16)v.y; dst[2] = (bf16)v.z; dst[3] = (bf16)v.w;
    }
    // u[batch] part: 64 rows x 16 chunks of 4 floats
    for (int i = tid; i < MT * 16; i += 256) {
        int row = i >> 4, c4 = (i & 15) * 4;
        int r = r0 + row;
        float4 v = make_float4(0.f, 0.f, 0.f, 0.f);
        if (r < N_NODES) {
            int g = batch[r];
            v = *(const float4*)(u + g * 64 + c4);
        }
        bf16* dst = &hA[row][192 + c4];
        dst[0] = (bf16)v.x; dst[1] = (bf16)v.y; dst[2] = (bf16)v.z; dst[3] = (bf16)v.w;
    }
    __syncthreads();

    gemm256<true>(hA, wT1, b1, hB);
    __syncthreads();
    gemm256<true>(hB, wT2, b2, hA);
    __syncthreads();
    gemm_out(hA, wT3, b3, out, r0);
}

// ---------------------------------------------------------------------------
extern "C" void kernel_launch(void* const* d_in, const int* in_sizes, int n_in,
                              void* d_out, int out_size, void* d_ws, size_t ws_size,
                              hipStream_t stream) {
    const float* x          = (const float*)d_in[0];
    const int*   edge_index = (const int*)d_in[1];
    const float* edge_attr  = (const float*)d_in[2];
    const float* u          = (const float*)d_in[3];
    const int*   batch      = (const int*)d_in[4];
    const float* w1         = (const float*)d_in[5];
    const float* b1         = (const float*)d_in[6];
    const float* w2         = (const float*)d_in[7];
    const float* b2         = (const float*)d_in[8];
    const float* w3         = (const float*)d_in[9];
    const float* b3         = (const float*)d_in[10];
    float* out = (float*)d_out;

    // Workspace layout: agg fp32 [50000][64], then transposed bf16 weights.
    float* agg = (float*)d_ws;
    size_t agg_bytes = (size_t)N_NODES * 64 * sizeof(float);   // 12.8 MB
    bf16* wT1 = (bf16*)((char*)d_ws + agg_bytes);
    bf16* wT2 = wT1 + 256 * 256;
    bf16* wT3 = wT2 + 256 * 256;

    hipMemsetAsync(d_ws, 0, agg_bytes, stream);

    transpose_w<<<640, 256, 0, stream>>>(w1, w2, w3, wT1, wT2, wT3);

    // col = edge_index row 1
    scatter_kernel<<<(N_EDGES * 64) / 256, 256, 0, stream>>>(
        edge_attr, edge_index + N_EDGES, agg);

    mlp_kernel<<<(N_NODES + MT - 1) / MT, 256, 0, stream>>>(
        x, agg, u, batch, wT1, b1, wT2, b2, wT3, b3, out);
}